// Round 5
// baseline (2768.801 us; speedup 1.0000x reference)
//
#include <hip/hip_runtime.h>
#include <stdint.h>

#define B_    256
#define SE    49
#define TD    25
#define INDIM 69
#define RNN   2048
#define NZ    64
#define G3    6144

typedef __attribute__((ext_vector_type(8))) short short8_t;
typedef __attribute__((ext_vector_type(4))) float f32x4;
typedef unsigned short u16;

__device__ __forceinline__ u16 f2b(float f) {
  union { float f; unsigned u; } c; c.f = f;
  unsigned u = c.u;
  return (u16)((u + 0x7FFFu + ((u >> 16) & 1u)) >> 16);
}
__device__ __forceinline__ float sigm(float x) { return 1.f / (1.f + __expf(-x)); }
__device__ __forceinline__ short8_t ldbf(const u16* __restrict__ p, size_t off) {
  return *(const short8_t*)&p[off];
}

// reordered row R -> original row of [3*RNN];  R = bn*96 + nw*48 + gate*16 + jj
__device__ __forceinline__ int rmap(int R) {
  int bn = R / 96, rem = R % 96;
  int nw = rem / 48, g = (rem % 48) / 16, jj = rem % 16;
  return g * RNN + bn * 32 + nw * 16 + jj;
}

// ===========================================================================
// prep kernels
// ===========================================================================
__global__ void k_reorder(const float* __restrict__ src, u16* __restrict__ dst, int K, int Kp) {
  int total = G3 * Kp;
  for (int i = blockIdx.x * blockDim.x + threadIdx.x; i < total; i += gridDim.x * blockDim.x) {
    int R = i / Kp, c = i % Kp;
    dst[i] = (c < K) ? f2b(src[(size_t)rmap(R) * K + c]) : (u16)0;
  }
}

// fc0T[256][2048]: r<138 -> fc0_w[k][r]; r==138 -> fc0_b[k]; else 0
__global__ void k_fc0T(const float* __restrict__ fc0w, const float* __restrict__ fc0b,
                       u16* __restrict__ dst) {
  int total = 256 * RNN;
  for (int i = blockIdx.x * blockDim.x + threadIdx.x; i < total; i += gridDim.x * blockDim.x) {
    int r = i >> 11, k = i & (RNN - 1);
    float v = 0.f;
    if (r < 2 * INDIM) v = fc0w[(size_t)k * (2 * INDIM) + r];
    else if (r == 2 * INDIM) v = fc0b[k];
    dst[i] = f2b(v);
  }
}

__global__ void k_fc2T(const float* __restrict__ fc2w, u16* __restrict__ dst) {
  int total = 96 * RNN;
  for (int i = blockIdx.x * blockDim.x + threadIdx.x; i < total; i += gridDim.x * blockDim.x) {
    int r = i >> 11, k = i & (RNN - 1);
    dst[i] = (r < INDIM) ? f2b(fc2w[(size_t)r * RNN + k]) : (u16)0;
  }
}

// pairs[49][256][256]: [0:69]=enc[b][t], [69:138]=next, [138]=1.0 (bias lane), pad 0
__global__ void k_pairs(const float* __restrict__ enc, const float* __restrict__ dec,
                        u16* __restrict__ pairs) {
  int total = SE * B_ * 256;
  for (int i = blockIdx.x * blockDim.x + threadIdx.x; i < total; i += gridDim.x * blockDim.x) {
    int c = i & 255, rb = i >> 8;
    int b = rb & 255, t = rb >> 8;
    float v = 0.f;
    if (c < INDIM) v = enc[((size_t)b * SE + t) * INDIM + c];
    else if (c < 2 * INDIM) {
      int cc = c - INDIM;
      v = (t < SE - 1) ? enc[((size_t)b * SE + t + 1) * INDIM + cc]
                       : dec[(size_t)b * TD * INDIM + cc];
    } else if (c == 2 * INDIM) v = 1.0f;
    pairs[i] = f2b(v);
  }
}

// msB[128][2048] bf16: n<64 -> mu_w[n][k], else sg_w[n-64][k]
__global__ void k_msB(const float* __restrict__ muw, const float* __restrict__ sgw,
                      u16* __restrict__ dst) {
  int total = 128 * RNN;
  for (int i = blockIdx.x * blockDim.x + threadIdx.x; i < total; i += gridDim.x * blockDim.x) {
    int n = i >> 11, k = i & (RNN - 1);
    dst[i] = (n < NZ) ? f2b(muw[(size_t)n * RNN + k]) : f2b(sgw[(size_t)(n - NZ) * RNN + k]);
  }
}

// fc1wB[2048][192] bf16 (K padded 133->192)
__global__ void k_fc1B(const float* __restrict__ w, u16* __restrict__ dst) {
  int total = RNN * 192;
  for (int i = blockIdx.x * blockDim.x + threadIdx.x; i < total; i += gridDim.x * blockDim.x) {
    int n = i / 192, k = i % 192;
    dst[i] = (k < NZ + INDIM) ? f2b(w[(size_t)n * (NZ + INDIM) + k]) : (u16)0;
  }
}

// biases (ebi now = bih only; wih1@fc0_b folded into Wenc col 138)
__global__ void k_bias(const float* __restrict__ c1bih, const float* __restrict__ c1bhh,
                       const float* __restrict__ c2wih, const float* __restrict__ fc2b,
                       const float* __restrict__ c2bih, const float* __restrict__ c2bhh,
                       float* __restrict__ ebi, float* __restrict__ ebh,
                       float* __restrict__ dbi0, float* __restrict__ dbi1, float* __restrict__ dbh) {
  int R = blockIdx.x * blockDim.x + threadIdx.x;
  if (R >= G3) return;
  int orig = rmap(R);
  float k3 = 0.f;
  for (int o = 0; o < INDIM; ++o) k3 += c2wih[(size_t)orig * INDIM + o] * fc2b[o];
  ebi[R] = c1bih[orig];
  ebh[R] = c1bhh[orig];
  float d0 = c2bih[orig];
  dbi0[R] = d0;
  dbi1[R] = d0 + k3;
  dbh[R] = c2bhh[orig];
}

// zero h slot0, fbuf[3], out_mu, out_lv
__global__ void k_init(float* __restrict__ hf, u16* __restrict__ hbf, float* __restrict__ fbuf,
                       float* __restrict__ omu, float* __restrict__ olv) {
  int i = blockIdx.x * blockDim.x + threadIdx.x;
  if (i < B_ * RNN) { hf[i] = 0.f; hbf[i] = 0; }
  if (i < 3 * B_ * 96) fbuf[i] = 0.f;
  if (i < B_ * NZ) { omu[i] = 0.f; olv[i] = 0.f; }
}

// ---------------------------------------------------------------------------
// bulk GEMM (r1-proven): Wenc = wih1_r @ fc0T^T  (M=6144, N=256, K=2048)
// ---------------------------------------------------------------------------
__global__ __launch_bounds__(256) void gemm_bt(
    const u16* __restrict__ A, const u16* __restrict__ W,
    u16* __restrict__ Cb, int N, int K)
{
  constexpr int BM = 128, BN = 128, BK = 64, LDK = BK + 8;
  __shared__ u16 sA[BM * LDK];
  __shared__ u16 sW[BN * LDK];
  const int ntn = N / BN;
  const int bm = blockIdx.x / ntn, bn = blockIdx.x % ntn;
  const int tid = threadIdx.x, lane = tid & 63, wave = tid >> 6;
  const int wr = wave >> 1, wc = wave & 1;
  f32x4 acc[4][4];
#pragma unroll
  for (int i = 0; i < 4; ++i)
#pragma unroll
    for (int j = 0; j < 4; ++j) acc[i][j] = (f32x4)(0.f);
  const int frow = lane & 15, fkq = (lane >> 4) * 8;
  for (int k0 = 0; k0 < K; k0 += BK) {
#pragma unroll
    for (int p = 0; p < 4; ++p) {
      int e = (p * 256 + tid) * 8, r = e / BK, c = e % BK;
      *(short8_t*)&sA[r * LDK + c] = *(const short8_t*)&A[(size_t)(bm * BM + r) * K + k0 + c];
    }
#pragma unroll
    for (int p = 0; p < 4; ++p) {
      int e = (p * 256 + tid) * 8, r = e / BK, c = e % BK;
      *(short8_t*)&sW[r * LDK + c] = *(const short8_t*)&W[(size_t)(bn * BN + r) * K + k0 + c];
    }
    __syncthreads();
#pragma unroll
    for (int kk = 0; kk < BK; kk += 32) {
      short8_t fa[4], fb[4];
#pragma unroll
      for (int m = 0; m < 4; ++m) fa[m] = *(const short8_t*)&sA[(wr * 64 + m * 16 + frow) * LDK + kk + fkq];
#pragma unroll
      for (int n = 0; n < 4; ++n) fb[n] = *(const short8_t*)&sW[(wc * 64 + n * 16 + frow) * LDK + kk + fkq];
#pragma unroll
      for (int m = 0; m < 4; ++m)
#pragma unroll
        for (int n = 0; n < 4; ++n)
          acc[m][n] = __builtin_amdgcn_mfma_f32_16x16x32_bf16(fa[m], fb[n], acc[m][n], 0, 0, 0);
    }
    __syncthreads();
  }
  const int crow = (lane >> 4) * 4, ccol = lane & 15;
#pragma unroll
  for (int n = 0; n < 4; ++n) {
    int col = bn * BN + wc * 64 + n * 16 + ccol;
#pragma unroll
    for (int m = 0; m < 4; ++m)
#pragma unroll
      for (int r = 0; r < 4; ++r) {
        int rowi = bm * BM + wr * 64 + m * 16 + crow + r;
        Cb[(size_t)rowi * N + col] = f2b(acc[m][n][r]);
      }
  }
}

// ===========================================================================
// step kernels: grid 256 (XCD-swizzled bm4 x bn64), block 512 = 8 waves (kg4 x nw2)
// GEMM core is LDS-free / barrier-free: direct-global MFMA fragments.
// LDS (64 KB) only for the end-of-step k-reduce.
// ===========================================================================
struct Args {
  const u16 *pairs, *Wenc, *whh1, *whh2, *wih2, *fc2T;
  const u16 *msB, *fc1wB;
  const float *ebi, *ebh, *dbi0, *dbi1, *dbh;
  const float *eps, *dec, *fc1_b, *fc2_b, *mu_b, *sg_b;
  float* hf;    // [2][256][2048]
  u16*   hbf;   // [2][256][2048]
  float* fbuf;  // [3][256][96]
  float* inp;   // [2][256][69]
  u16*   inpbf; // [2][256][128]
  u16*   fc1xB; // [256][192]
  float *out, *out_mu, *out_lv;
};

// 4-wave k-split reduce (3 LDS rounds) + in-register GRU gate on waves 0,1
__device__ __forceinline__ void reduce_and_gate(
    f32x4 (&aR)[4], f32x4 (&aZ)[4], f32x4 (&aNI)[4], f32x4 (&aNH)[4],
    char* smem, int tid, int bm, int bn,
    const float* __restrict__ bi, const float* __restrict__ bh,
    const float* __restrict__ hfold, float* __restrict__ hfnew, u16* __restrict__ hbnew) {
  const int lane = tid & 63, wid = tid >> 6;
  auto wr16 = [&](int slots, int w) {
#pragma unroll
    for (int m = 0; m < 4; ++m) {
      *(f32x4*)&smem[(((0 * 4 + m) * slots + w) * 64 + lane) * 16] = aR[m];
      *(f32x4*)&smem[(((1 * 4 + m) * slots + w) * 64 + lane) * 16] = aZ[m];
      *(f32x4*)&smem[(((2 * 4 + m) * slots + w) * 64 + lane) * 16] = aNI[m];
      *(f32x4*)&smem[(((3 * 4 + m) * slots + w) * 64 + lane) * 16] = aNH[m];
    }
  };
  auto add16 = [&](int slots, int w) {
#pragma unroll
    for (int m = 0; m < 4; ++m) {
      aR[m]  += *(const f32x4*)&smem[(((0 * 4 + m) * slots + w) * 64 + lane) * 16];
      aZ[m]  += *(const f32x4*)&smem[(((1 * 4 + m) * slots + w) * 64 + lane) * 16];
      aNI[m] += *(const f32x4*)&smem[(((2 * 4 + m) * slots + w) * 64 + lane) * 16];
      aNH[m] += *(const f32x4*)&smem[(((3 * 4 + m) * slots + w) * 64 + lane) * 16];
    }
  };
  __syncthreads();
  if (wid >= 4) wr16(4, wid - 4);
  __syncthreads();
  if (wid < 4) add16(4, wid);
  __syncthreads();
  if (wid == 2 || wid == 3) wr16(2, wid - 2);
  __syncthreads();
  if (wid < 2) {
    add16(2, wid);
    const int nw = wid, jj = lane & 15;
    const int Rb = bn * 96 + nw * 48;
    const float biR = bi[Rb + jj],      bhR = bh[Rb + jj];
    const float biZ = bi[Rb + 16 + jj], bhZ = bh[Rb + 16 + jj];
    const float biN = bi[Rb + 32 + jj], bhN = bh[Rb + 32 + jj];
    const int j = bn * 32 + nw * 16 + jj;
#pragma unroll
    for (int m = 0; m < 4; ++m)
#pragma unroll
      for (int q = 0; q < 4; ++q) {
        int b = bm * 64 + m * 16 + ((lane >> 4) << 2) + q;
        float r = sigm(aR[m][q] + biR + bhR);
        float z = sigm(aZ[m][q] + biZ + bhZ);
        float nn = 2.f * sigm(2.f * ((aNI[m][q] + biN) + r * (aNH[m][q] + bhN))) - 1.f;
        float hv = (1.f - z) * nn + z * hfold[(size_t)b * RNN + j];
        hfnew[(size_t)b * RNN + j] = hv;
        hbnew[(size_t)b * RNN + j] = f2b(hv);
      }
  }
}

// ---- encoder step ---------------------------------------------------------
__global__ __launch_bounds__(512, 1) void k_enc(Args a, int t) {
  __shared__ char smem[65536];
  const int tid = threadIdx.x, lane = tid & 63, wid = tid >> 6;
  const int kg = wid >> 1, nw = wid & 1;
  const int bid = blockIdx.x;
  const int bm = (bid >> 3) & 3;
  const int bn = (bid & 7) | ((bid >> 5) << 3);   // XCD swizzle: 4 bm-blocks of a bn share xcd
  const int rowA0 = bm * 64, rowW0 = bn * 96 + nw * 48;
  const int fr = lane & 15, fq = (lane >> 4) << 3;
  const int pin = t & 1, pout = pin ^ 1;
  const u16* hin = a.hbf + (size_t)pin * B_ * RNN;
  const float* hfold = a.hf + (size_t)pin * B_ * RNN;
  float* hfnew = a.hf + (size_t)pout * B_ * RNN;
  u16* hbnew = a.hbf + (size_t)pout * B_ * RNN;

  f32x4 aR[4], aZ[4], aNI[4], aNH[4];
#pragma unroll
  for (int m = 0; m < 4; ++m) {
    aR[m] = (f32x4)(0.f); aZ[m] = (f32x4)(0.f);
    aNI[m] = (f32x4)(0.f); aNH[m] = (f32x4)(0.f);
  }

  // ---- gi: pairs[t] @ Wenc^T, K=256 (wave slice 64) -> aR,aZ,aNI ----
  const u16* P = a.pairs + (size_t)t * B_ * 256;
#pragma unroll
  for (int ks = 0; ks < 2; ++ks) {
    const int k = kg * 64 + ks * 32 + fq;
    short8_t fa[4], fb[3];
#pragma unroll
    for (int m = 0; m < 4; ++m) fa[m] = ldbf(P, (size_t)(rowA0 + m * 16 + fr) * 256 + k);
#pragma unroll
    for (int g = 0; g < 3; ++g) fb[g] = ldbf(a.Wenc, (size_t)(rowW0 + g * 16 + fr) * 256 + k);
#pragma unroll
    for (int m = 0; m < 4; ++m) {
      aR[m]  = __builtin_amdgcn_mfma_f32_16x16x32_bf16(fa[m], fb[0], aR[m], 0, 0, 0);
      aZ[m]  = __builtin_amdgcn_mfma_f32_16x16x32_bf16(fa[m], fb[1], aZ[m], 0, 0, 0);
      aNI[m] = __builtin_amdgcn_mfma_f32_16x16x32_bf16(fa[m], fb[2], aNI[m], 0, 0, 0);
    }
  }
  // ---- gh: h @ whh1^T, K=2048 (wave slice 512) -> aR,aZ,aNH ----
  const int kb = kg * 512;
#pragma unroll 4
  for (int ks = 0; ks < 16; ++ks) {
    const int k = kb + ks * 32 + fq;
    short8_t fa[4], fb[3];
#pragma unroll
    for (int m = 0; m < 4; ++m) fa[m] = ldbf(hin, (size_t)(rowA0 + m * 16 + fr) * RNN + k);
#pragma unroll
    for (int g = 0; g < 3; ++g) fb[g] = ldbf(a.whh1, (size_t)(rowW0 + g * 16 + fr) * RNN + k);
#pragma unroll
    for (int m = 0; m < 4; ++m) {
      aR[m]  = __builtin_amdgcn_mfma_f32_16x16x32_bf16(fa[m], fb[0], aR[m], 0, 0, 0);
      aZ[m]  = __builtin_amdgcn_mfma_f32_16x16x32_bf16(fa[m], fb[1], aZ[m], 0, 0, 0);
      aNH[m] = __builtin_amdgcn_mfma_f32_16x16x32_bf16(fa[m], fb[2], aNH[m], 0, 0, 0);
    }
  }
  reduce_and_gate(aR, aZ, aNI, aNH, smem, tid, bm, bn, a.ebi, a.ebh, hfold, hfnew, hbnew);
}

// ---- decoder step ---------------------------------------------------------
__global__ __launch_bounds__(512, 1) void k_dec(Args a, int t) {
  __shared__ char smem[65536];
  const int tid = threadIdx.x, lane = tid & 63, wid = tid >> 6;
  const int kg = wid >> 1, nw = wid & 1;
  const int bid = blockIdx.x;
  const int bm = (bid >> 3) & 3;
  const int bn = (bid & 7) | ((bid >> 5) << 3);
  const int rowA0 = bm * 64, rowW0 = bn * 96 + nw * 48;
  const int fr = lane & 15, fq = (lane >> 4) << 3;
  const int pin = t & 1, pout = pin ^ 1;
  const int irs = (t + 1) & 1, iws = t & 1;
  const int frd = (t + 2) % 3;
  const u16* hin = a.hbf + (size_t)pin * B_ * RNN;
  const float* hfold = a.hf + (size_t)pin * B_ * RNN;
  float* hfnew = a.hf + (size_t)pout * B_ * RNN;
  u16* hbnew = a.hbf + (size_t)pout * B_ * RNN;
  const int gtid = bid * 512 + tid;

  // epilogue: out_{t-1} = inp_{t-1} + f_{t-1} + fc2_b ; write inp_t
  if (t >= 1 && gtid < B_ * INDIM) {
    int b = gtid / INDIM, o = gtid % INDIM;
    float v = a.inp[(size_t)irs * B_ * INDIM + gtid] +
              a.fbuf[(size_t)frd * B_ * 96 + b * 96 + o] + a.fc2_b[o];
    a.out[((size_t)b * TD + (t - 1)) * INDIM + o] = v;
    a.inp[(size_t)iws * B_ * INDIM + gtid] = v;
    a.inpbf[(size_t)iws * B_ * 128 + b * 128 + o] = f2b(v);
  }
  // zero f slot for step t+1
  if (gtid < B_ * 96)
    a.fbuf[(size_t)((t + 1) % 3) * B_ * 96 + gtid] = 0.f;

  f32x4 aR[4], aZ[4], aNI[4], aNH[4];
#pragma unroll
  for (int m = 0; m < 4; ++m) {
    aR[m] = (f32x4)(0.f); aZ[m] = (f32x4)(0.f);
    aNI[m] = (f32x4)(0.f); aNH[m] = (f32x4)(0.f);
  }

  // ---- gi: [inp | f_{t-1}] @ [wih2;wih2]^T, K=256 (wave slice 64) ----
  if (kg < 2) {
    const u16* inpA = a.inpbf + (size_t)irs * B_ * 128;
#pragma unroll
    for (int ks = 0; ks < 2; ++ks) {
      const int k = kg * 64 + ks * 32 + fq;
      short8_t fa[4], fb[3];
#pragma unroll
      for (int m = 0; m < 4; ++m) fa[m] = ldbf(inpA, (size_t)(rowA0 + m * 16 + fr) * 128 + k);
#pragma unroll
      for (int g = 0; g < 3; ++g) fb[g] = ldbf(a.wih2, (size_t)(rowW0 + g * 16 + fr) * 128 + k);
#pragma unroll
      for (int m = 0; m < 4; ++m) {
        aR[m]  = __builtin_amdgcn_mfma_f32_16x16x32_bf16(fa[m], fb[0], aR[m], 0, 0, 0);
        aZ[m]  = __builtin_amdgcn_mfma_f32_16x16x32_bf16(fa[m], fb[1], aZ[m], 0, 0, 0);
        aNI[m] = __builtin_amdgcn_mfma_f32_16x16x32_bf16(fa[m], fb[2], aNI[m], 0, 0, 0);
      }
    }
  } else {
    const float* F = a.fbuf + (size_t)frd * B_ * 96;
#pragma unroll
    for (int ks = 0; ks < 2; ++ks) {
      if (kg == 3 && ks == 1) continue;   // pad-only region (cols 96..127)
      const int kw = (kg - 2) * 64 + ks * 32 + fq;   // f col == wih2 col
      short8_t fa[4], fb[3];
#pragma unroll
      for (int m = 0; m < 4; ++m) {
        const int rrow = rowA0 + m * 16 + fr;
        f32x4 v0 = *(const f32x4*)&F[(size_t)rrow * 96 + kw];
        f32x4 v1 = *(const f32x4*)&F[(size_t)rrow * 96 + kw + 4];
        short8_t v;
        v[0] = (short)f2b(v0[0]); v[1] = (short)f2b(v0[1]);
        v[2] = (short)f2b(v0[2]); v[3] = (short)f2b(v0[3]);
        v[4] = (short)f2b(v1[0]); v[5] = (short)f2b(v1[1]);
        v[6] = (short)f2b(v1[2]); v[7] = (short)f2b(v1[3]);
        fa[m] = v;
      }
#pragma unroll
      for (int g = 0; g < 3; ++g) fb[g] = ldbf(a.wih2, (size_t)(rowW0 + g * 16 + fr) * 128 + kw);
#pragma unroll
      for (int m = 0; m < 4; ++m) {
        aR[m]  = __builtin_amdgcn_mfma_f32_16x16x32_bf16(fa[m], fb[0], aR[m], 0, 0, 0);
        aZ[m]  = __builtin_amdgcn_mfma_f32_16x16x32_bf16(fa[m], fb[1], aZ[m], 0, 0, 0);
        aNI[m] = __builtin_amdgcn_mfma_f32_16x16x32_bf16(fa[m], fb[2], aNI[m], 0, 0, 0);
      }
    }
  }
  // ---- gh: h @ whh2^T, K=2048 ----
  const int kb = kg * 512;
#pragma unroll 4
  for (int ks = 0; ks < 16; ++ks) {
    const int k = kb + ks * 32 + fq;
    short8_t fa[4], fb[3];
#pragma unroll
    for (int m = 0; m < 4; ++m) fa[m] = ldbf(hin, (size_t)(rowA0 + m * 16 + fr) * RNN + k);
#pragma unroll
    for (int g = 0; g < 3; ++g) fb[g] = ldbf(a.whh2, (size_t)(rowW0 + g * 16 + fr) * RNN + k);
#pragma unroll
    for (int m = 0; m < 4; ++m) {
      aR[m]  = __builtin_amdgcn_mfma_f32_16x16x32_bf16(fa[m], fb[0], aR[m], 0, 0, 0);
      aZ[m]  = __builtin_amdgcn_mfma_f32_16x16x32_bf16(fa[m], fb[1], aZ[m], 0, 0, 0);
      aNH[m] = __builtin_amdgcn_mfma_f32_16x16x32_bf16(fa[m], fb[2], aNH[m], 0, 0, 0);
    }
  }
  reduce_and_gate(aR, aZ, aNI, aNH, smem, tid, bm, bn,
                  (t >= 1) ? a.dbi1 : a.dbi0, a.dbh, hfold, hfnew, hbnew);

  // ---- f_t partial: fbuf[t%3][bm rows][96] += h'[rows][k=bn*32..] @ fc2T^T
  __syncthreads();   // drain h' global writes (block-local visibility)
  if (wid < 4) {
    const int wr = wid >> 1, wc = wid & 1;
    const int kcol = bn * 32 + fq;
    short8_t fa[2], fb[3];
#pragma unroll
    for (int m = 0; m < 2; ++m)
      fa[m] = ldbf(hbnew, (size_t)(bm * 64 + wr * 32 + m * 16 + fr) * RNN + kcol);
#pragma unroll
    for (int n = 0; n < 3; ++n)
      fb[n] = ldbf(a.fc2T, (size_t)(wc * 48 + n * 16 + fr) * RNN + kcol);
    f32x4 accf[2][3];
#pragma unroll
    for (int m = 0; m < 2; ++m)
#pragma unroll
      for (int n = 0; n < 3; ++n) accf[m][n] = (f32x4)(0.f);
#pragma unroll
    for (int m = 0; m < 2; ++m)
#pragma unroll
      for (int n = 0; n < 3; ++n)
        accf[m][n] = __builtin_amdgcn_mfma_f32_16x16x32_bf16(fa[m], fb[n], accf[m][n], 0, 0, 0);
    float* fdst = a.fbuf + (size_t)(t % 3) * B_ * 96;
#pragma unroll
    for (int m = 0; m < 2; ++m)
#pragma unroll
      for (int n = 0; n < 3; ++n)
#pragma unroll
        for (int q = 0; q < 4; ++q) {
          int row = bm * 64 + wr * 32 + m * 16 + ((lane >> 4) << 2) + q;
          int col = wc * 48 + n * 16 + (lane & 15);
          atomicAdd(&fdst[row * 96 + col], accf[m][n][q]);
        }
  }
}

// ---- latent mu/sigma MFMA: out[256][128] += h1 @ msB^T (k-split atomics) ----
__global__ __launch_bounds__(256) void k_msm(Args a) {
  const int bm = blockIdx.x >> 3, kc = blockIdx.x & 7;
  const int lane = threadIdx.x & 63, wid = threadIdx.x >> 6;
  const int wr = wid >> 1, wc = wid & 1;
  const int fr = lane & 15, fq = (lane >> 4) << 3;
  const u16* h1 = a.hbf + (size_t)B_ * RNN;   // enc final = slot 1
  f32x4 acc[4][4];
#pragma unroll
  for (int m = 0; m < 4; ++m)
#pragma unroll
    for (int n = 0; n < 4; ++n) acc[m][n] = (f32x4)(0.f);
#pragma unroll
  for (int ks = 0; ks < 8; ++ks) {
    const int k = kc * 256 + ks * 32 + fq;
    short8_t fa[4], fb[4];
#pragma unroll
    for (int m = 0; m < 4; ++m)
      fa[m] = ldbf(h1, (size_t)(bm * 128 + wr * 64 + m * 16 + fr) * RNN + k);
#pragma unroll
    for (int n = 0; n < 4; ++n)
      fb[n] = ldbf(a.msB, (size_t)(wc * 64 + n * 16 + fr) * RNN + k);
#pragma unroll
    for (int m = 0; m < 4; ++m)
#pragma unroll
      for (int n = 0; n < 4; ++n)
        acc[m][n] = __builtin_amdgcn_mfma_f32_16x16x32_bf16(fa[m], fb[n], acc[m][n], 0, 0, 0);
  }
#pragma unroll
  for (int m = 0; m < 4; ++m)
#pragma unroll
    for (int n = 0; n < 4; ++n)
#pragma unroll
      for (int q = 0; q < 4; ++q) {
        int row = bm * 128 + wr * 64 + m * 16 + ((lane >> 4) << 2) + q;
        int col = wc * 64 + n * 16 + (lane & 15);
        if (col < NZ) atomicAdd(&a.out_mu[row * NZ + col], acc[m][n][q]);
        else          atomicAdd(&a.out_lv[row * NZ + col - NZ], acc[m][n][q]);
      }
}

// ---- sample + fc1 input + decoder inp init --------------------------------
__global__ void k_sample(Args a) {
  int gid = blockIdx.x * blockDim.x + threadIdx.x;
  if (gid < B_ * NZ) {
    int b = gid >> 6, n = gid & 63;
    float mu = a.out_mu[gid] + a.mu_b[n];
    float lv = a.out_lv[gid] + a.sg_b[n];
    a.out_mu[gid] = mu;
    a.out_lv[gid] = lv;
    a.fc1xB[b * 192 + n] = f2b(mu + a.eps[gid] * __expf(0.5f * lv));
  }
  if (gid < B_ * 128) {
    int b = gid >> 7, c = gid & 127;
    float v = (c < INDIM) ? a.dec[(size_t)b * TD * INDIM + c] : 0.f;
    u16 vb = f2b(v);
    a.inpbf[(size_t)b * 128 + c] = vb;
    a.inpbf[(size_t)B_ * 128 + b * 128 + c] = vb;
    if (c < INDIM) {
      a.inp[b * INDIM + c] = v;
      a.inp[B_ * INDIM + b * INDIM + c] = v;
      a.fc1xB[b * 192 + NZ + c] = f2b(v);
    }
  }
  if (gid < B_ * 192) {
    int c = gid % 192;
    if (c >= NZ + INDIM) a.fc1xB[gid] = 0;
  }
}

// ---- fc1 MFMA: h0 = fc1xB @ fc1wB^T + b  (M=256,N=2048,K=192) --------------
__global__ __launch_bounds__(256) void k_fc1m(Args a) {
  const int bm = blockIdx.x >> 4, bn = blockIdx.x & 15;
  const int lane = threadIdx.x & 63, wid = threadIdx.x >> 6;
  const int wr = wid >> 1, wc = wid & 1;
  const int fr = lane & 15, fq = (lane >> 4) << 3;
  f32x4 acc[4][4];
#pragma unroll
  for (int m = 0; m < 4; ++m)
#pragma unroll
    for (int n = 0; n < 4; ++n) acc[m][n] = (f32x4)(0.f);
#pragma unroll
  for (int ks = 0; ks < 6; ++ks) {
    const int k = ks * 32 + fq;
    short8_t fa[4], fb[4];
#pragma unroll
    for (int m = 0; m < 4; ++m)
      fa[m] = ldbf(a.fc1xB, (size_t)(bm * 128 + wr * 64 + m * 16 + fr) * 192 + k);
#pragma unroll
    for (int n = 0; n < 4; ++n)
      fb[n] = ldbf(a.fc1wB, (size_t)(bn * 128 + wc * 64 + n * 16 + fr) * 192 + k);
#pragma unroll
    for (int m = 0; m < 4; ++m)
#pragma unroll
      for (int n = 0; n < 4; ++n)
        acc[m][n] = __builtin_amdgcn_mfma_f32_16x16x32_bf16(fa[m], fb[n], acc[m][n], 0, 0, 0);
  }
#pragma unroll
  for (int n = 0; n < 4; ++n) {
    const int col = bn * 128 + wc * 64 + n * 16 + (lane & 15);
    const float bv = a.fc1_b[col];
#pragma unroll
    for (int m = 0; m < 4; ++m)
#pragma unroll
      for (int q = 0; q < 4; ++q) {
        int row = bm * 128 + wr * 64 + m * 16 + ((lane >> 4) << 2) + q;
        float v = acc[m][n][q] + bv;
        a.hf[(size_t)row * RNN + col] = v;      // slot 0
        a.hbf[(size_t)row * RNN + col] = f2b(v);
      }
  }
}

// ---- tail: out_24 ----------------------------------------------------------
__global__ void k_tail(Args a) {
  int i = blockIdx.x * blockDim.x + threadIdx.x;
  if (i < B_ * INDIM) {
    int b = i / INDIM, o = i % INDIM;
    float v = a.inp[(size_t)(24 & 1) * B_ * INDIM + i] +
              a.fbuf[(size_t)(24 % 3) * B_ * 96 + b * 96 + o] + a.fc2_b[o];
    a.out[((size_t)b * TD + 24) * INDIM + o] = v;
  }
}

// ===========================================================================
extern "C" void kernel_launch(void* const* d_in, const int* in_sizes, int n_in,
                              void* d_out, int out_size, void* d_ws, size_t ws_size,
                              hipStream_t stream)
{
  const float* enc    = (const float*)d_in[0];
  const float* dec    = (const float*)d_in[1];
  const float* eps    = (const float*)d_in[2];
  const float* fc0_w  = (const float*)d_in[3];
  const float* fc0_b  = (const float*)d_in[4];
  const float* fc1_w  = (const float*)d_in[5];
  const float* fc1_b  = (const float*)d_in[6];
  const float* fc2_w  = (const float*)d_in[7];
  const float* fc2_b  = (const float*)d_in[8];
  const float* mu_w   = (const float*)d_in[9];
  const float* mu_b   = (const float*)d_in[10];
  const float* sg_w   = (const float*)d_in[11];
  const float* sg_b   = (const float*)d_in[12];
  const float* c1_wih = (const float*)d_in[13];
  const float* c1_whh = (const float*)d_in[14];
  const float* c1_bih = (const float*)d_in[15];
  const float* c1_bhh = (const float*)d_in[16];
  const float* c2_wih = (const float*)d_in[17];
  const float* c2_whh = (const float*)d_in[18];
  const float* c2_bih = (const float*)d_in[19];
  const float* c2_bhh = (const float*)d_in[20];

  float* out_outputs = (float*)d_out;
  float* out_mu = out_outputs + (size_t)B_ * TD * INDIM;
  float* out_lv = out_mu + (size_t)B_ * NZ;

  char* ws = (char*)d_ws;
  size_t off = 0;
  auto alloc = [&](size_t bytes) -> void* {
    void* p = ws + off; off += (bytes + 255) & ~(size_t)255; return p;
  };

  u16* whh1_r = (u16*)alloc((size_t)G3 * RNN * 2);
  u16* whh2_r = (u16*)alloc((size_t)G3 * RNN * 2);
  u16* wih1_r = (u16*)alloc((size_t)G3 * RNN * 2);
  u16* wih2_r = (u16*)alloc((size_t)G3 * 128 * 2);
  u16* fc0T   = (u16*)alloc((size_t)256 * RNN * 2);
  u16* fc2T   = (u16*)alloc((size_t)96 * RNN * 2);
  u16* Wenc   = (u16*)alloc((size_t)G3 * 256 * 2);
  u16* pairs  = (u16*)alloc((size_t)SE * B_ * 256 * 2);
  u16* msB    = (u16*)alloc((size_t)128 * RNN * 2);
  u16* fc1wB  = (u16*)alloc((size_t)RNN * 192 * 2);
  float* hf   = (float*)alloc((size_t)2 * B_ * RNN * 4);
  u16* hbf    = (u16*)alloc((size_t)2 * B_ * RNN * 2);
  float* fbuf = (float*)alloc((size_t)3 * B_ * 96 * 4);
  float* inp  = (float*)alloc((size_t)2 * B_ * INDIM * 4);
  u16* inpbf  = (u16*)alloc((size_t)2 * B_ * 128 * 2);
  u16* fc1xB  = (u16*)alloc((size_t)B_ * 192 * 2);
  float* ebi  = (float*)alloc((size_t)G3 * 4);
  float* ebh  = (float*)alloc((size_t)G3 * 4);
  float* dbi0 = (float*)alloc((size_t)G3 * 4);
  float* dbi1 = (float*)alloc((size_t)G3 * 4);
  float* dbh  = (float*)alloc((size_t)G3 * 4);
  (void)ws_size; (void)in_sizes; (void)n_in; (void)out_size;

  // ---- prep ----
  k_reorder<<<4096, 256, 0, stream>>>(c1_whh, whh1_r, RNN, RNN);
  k_reorder<<<4096, 256, 0, stream>>>(c2_whh, whh2_r, RNN, RNN);
  k_reorder<<<4096, 256, 0, stream>>>(c1_wih, wih1_r, RNN, RNN);
  k_reorder<<<1024, 256, 0, stream>>>(c2_wih, wih2_r, INDIM, 128);
  k_fc0T<<<512, 256, 0, stream>>>(fc0_w, fc0_b, fc0T);
  k_fc2T<<<256, 256, 0, stream>>>(fc2_w, fc2T);
  k_pairs<<<2048, 256, 0, stream>>>(enc, dec, pairs);
  k_msB<<<256, 256, 0, stream>>>(mu_w, sg_w, msB);
  k_fc1B<<<256, 256, 0, stream>>>(fc1_w, fc1wB);
  k_bias<<<24, 256, 0, stream>>>(c1_bih, c1_bhh, c2_wih, fc2_b, c2_bih, c2_bhh,
                                 ebi, ebh, dbi0, dbi1, dbh);

  Args a;
  a.pairs = pairs; a.Wenc = Wenc; a.whh1 = whh1_r; a.whh2 = whh2_r;
  a.wih2 = wih2_r; a.fc2T = fc2T; a.msB = msB; a.fc1wB = fc1wB;
  a.ebi = ebi; a.ebh = ebh; a.dbi0 = dbi0; a.dbi1 = dbi1; a.dbh = dbh;
  a.eps = eps; a.dec = dec; a.fc1_b = fc1_b; a.fc2_b = fc2_b;
  a.mu_b = mu_b; a.sg_b = sg_b;
  a.hf = hf; a.hbf = hbf; a.fbuf = fbuf; a.inp = inp; a.inpbf = inpbf;
  a.fc1xB = fc1xB; a.out = out_outputs; a.out_mu = out_mu; a.out_lv = out_lv;

  k_init<<<2048, 256, 0, stream>>>(hf, hbf, fbuf, out_mu, out_lv);
  gemm_bt<<<(G3 / 128) * (256 / 128), 256, 0, stream>>>(wih1_r, fc0T, Wenc, 256, RNN);

  for (int t = 0; t < SE; ++t)
    k_enc<<<256, 512, 0, stream>>>(a, t);
  k_msm<<<16, 256, 0, stream>>>(a);
  k_sample<<<192, 256, 0, stream>>>(a);
  k_fc1m<<<32, 256, 0, stream>>>(a);
  for (int t = 0; t < TD; ++t)
    k_dec<<<256, 512, 0, stream>>>(a, t);
  k_tail<<<69, 256, 0, stream>>>(a);
}

// Round 6
// 1435.044 us; speedup vs baseline: 1.9294x; 1.9294x over previous
//
#include <hip/hip_runtime.h>
#include <stdint.h>

#define B_    256
#define SE    49
#define TD    25
#define INDIM 69
#define RNN   2048
#define NZ    64
#define G3    6144

typedef __attribute__((ext_vector_type(8))) short short8_t;
typedef __attribute__((ext_vector_type(4))) float f32x4;
typedef unsigned short u16;

#define BARRIER() do { asm volatile("s_waitcnt lgkmcnt(0)" ::: "memory"); \
                       __builtin_amdgcn_s_barrier(); } while (0)

__device__ __forceinline__ u16 f2b(float f) {
  union { float f; unsigned u; } c; c.f = f;
  unsigned u = c.u;
  return (u16)((u + 0x7FFFu + ((u >> 16) & 1u)) >> 16);
}
__device__ __forceinline__ float sigm(float x) { return 1.f / (1.f + __expf(-x)); }
__device__ __forceinline__ short8_t ldbf(const u16* __restrict__ p, size_t off) {
  return *(const short8_t*)&p[off];
}

// reordered row R -> original row of [3*RNN];  R = bn*96 + nw*48 + gate*16 + jj
__device__ __forceinline__ int rmap(int R) {
  int bn = R / 96, rem = R % 96;
  int nw = rem / 48, g = (rem % 48) / 16, jj = rem % 16;
  return g * RNN + bn * 32 + nw * 16 + jj;
}

// ===========================================================================
// prep kernels (r5-verified)
// ===========================================================================
__global__ void k_reorder(const float* __restrict__ src, u16* __restrict__ dst, int K, int Kp) {
  int total = G3 * Kp;
  for (int i = blockIdx.x * blockDim.x + threadIdx.x; i < total; i += gridDim.x * blockDim.x) {
    int R = i / Kp, c = i % Kp;
    dst[i] = (c < K) ? f2b(src[(size_t)rmap(R) * K + c]) : (u16)0;
  }
}

__global__ void k_fc0T(const float* __restrict__ fc0w, const float* __restrict__ fc0b,
                       u16* __restrict__ dst) {
  int total = 256 * RNN;
  for (int i = blockIdx.x * blockDim.x + threadIdx.x; i < total; i += gridDim.x * blockDim.x) {
    int r = i >> 11, k = i & (RNN - 1);
    float v = 0.f;
    if (r < 2 * INDIM) v = fc0w[(size_t)k * (2 * INDIM) + r];
    else if (r == 2 * INDIM) v = fc0b[k];
    dst[i] = f2b(v);
  }
}

__global__ void k_fc2T(const float* __restrict__ fc2w, u16* __restrict__ dst) {
  int total = 96 * RNN;
  for (int i = blockIdx.x * blockDim.x + threadIdx.x; i < total; i += gridDim.x * blockDim.x) {
    int r = i >> 11, k = i & (RNN - 1);
    dst[i] = (r < INDIM) ? f2b(fc2w[(size_t)r * RNN + k]) : (u16)0;
  }
}

__global__ void k_pairs(const float* __restrict__ enc, const float* __restrict__ dec,
                        u16* __restrict__ pairs) {
  int total = SE * B_ * 256;
  for (int i = blockIdx.x * blockDim.x + threadIdx.x; i < total; i += gridDim.x * blockDim.x) {
    int c = i & 255, rb = i >> 8;
    int b = rb & 255, t = rb >> 8;
    float v = 0.f;
    if (c < INDIM) v = enc[((size_t)b * SE + t) * INDIM + c];
    else if (c < 2 * INDIM) {
      int cc = c - INDIM;
      v = (t < SE - 1) ? enc[((size_t)b * SE + t + 1) * INDIM + cc]
                       : dec[(size_t)b * TD * INDIM + cc];
    } else if (c == 2 * INDIM) v = 1.0f;
    pairs[i] = f2b(v);
  }
}

__global__ void k_msB(const float* __restrict__ muw, const float* __restrict__ sgw,
                      u16* __restrict__ dst) {
  int total = 128 * RNN;
  for (int i = blockIdx.x * blockDim.x + threadIdx.x; i < total; i += gridDim.x * blockDim.x) {
    int n = i >> 11, k = i & (RNN - 1);
    dst[i] = (n < NZ) ? f2b(muw[(size_t)n * RNN + k]) : f2b(sgw[(size_t)(n - NZ) * RNN + k]);
  }
}

__global__ void k_fc1B(const float* __restrict__ w, u16* __restrict__ dst) {
  int total = RNN * 192;
  for (int i = blockIdx.x * blockDim.x + threadIdx.x; i < total; i += gridDim.x * blockDim.x) {
    int n = i / 192, k = i % 192;
    dst[i] = (k < NZ + INDIM) ? f2b(w[(size_t)n * (NZ + INDIM) + k]) : (u16)0;
  }
}

__global__ void k_bias(const float* __restrict__ c1bih, const float* __restrict__ c1bhh,
                       const float* __restrict__ c2wih, const float* __restrict__ fc2b,
                       const float* __restrict__ c2bih, const float* __restrict__ c2bhh,
                       float* __restrict__ ebi, float* __restrict__ ebh,
                       float* __restrict__ dbi0, float* __restrict__ dbi1, float* __restrict__ dbh) {
  int R = blockIdx.x * blockDim.x + threadIdx.x;
  if (R >= G3) return;
  int orig = rmap(R);
  float k3 = 0.f;
  for (int o = 0; o < INDIM; ++o) k3 += c2wih[(size_t)orig * INDIM + o] * fc2b[o];
  ebi[R] = c1bih[orig];
  ebh[R] = c1bhh[orig];
  float d0 = c2bih[orig];
  dbi0[R] = d0;
  dbi1[R] = d0 + k3;
  dbh[R] = c2bhh[orig];
}

__global__ void k_init(float* __restrict__ hf, u16* __restrict__ hbf, float* __restrict__ fbuf,
                       float* __restrict__ omu, float* __restrict__ olv) {
  int i = blockIdx.x * blockDim.x + threadIdx.x;
  if (i < B_ * RNN) { hf[i] = 0.f; hbf[i] = 0; }
  if (i < 3 * B_ * 96) fbuf[i] = 0.f;
  if (i < B_ * NZ) { omu[i] = 0.f; olv[i] = 0.f; }
}

// ---------------------------------------------------------------------------
// bulk GEMM (r1-proven): Wenc = wih1_r @ fc0T^T  (M=6144, N=256, K=2048)
// ---------------------------------------------------------------------------
__global__ __launch_bounds__(256) void gemm_bt(
    const u16* __restrict__ A, const u16* __restrict__ W,
    u16* __restrict__ Cb, int N, int K)
{
  constexpr int BM = 128, BN = 128, BK = 64, LDK = BK + 8;
  __shared__ u16 sA[BM * LDK];
  __shared__ u16 sW[BN * LDK];
  const int ntn = N / BN;
  const int bm = blockIdx.x / ntn, bn = blockIdx.x % ntn;
  const int tid = threadIdx.x, lane = tid & 63, wave = tid >> 6;
  const int wr = wave >> 1, wc = wave & 1;
  f32x4 acc[4][4];
#pragma unroll
  for (int i = 0; i < 4; ++i)
#pragma unroll
    for (int j = 0; j < 4; ++j) acc[i][j] = (f32x4)(0.f);
  const int frow = lane & 15, fkq = (lane >> 4) * 8;
  for (int k0 = 0; k0 < K; k0 += BK) {
#pragma unroll
    for (int p = 0; p < 4; ++p) {
      int e = (p * 256 + tid) * 8, r = e / BK, c = e % BK;
      *(short8_t*)&sA[r * LDK + c] = *(const short8_t*)&A[(size_t)(bm * BM + r) * K + k0 + c];
    }
#pragma unroll
    for (int p = 0; p < 4; ++p) {
      int e = (p * 256 + tid) * 8, r = e / BK, c = e % BK;
      *(short8_t*)&sW[r * LDK + c] = *(const short8_t*)&W[(size_t)(bn * BN + r) * K + k0 + c];
    }
    __syncthreads();
#pragma unroll
    for (int kk = 0; kk < BK; kk += 32) {
      short8_t fa[4], fb[4];
#pragma unroll
      for (int m = 0; m < 4; ++m) fa[m] = *(const short8_t*)&sA[(wr * 64 + m * 16 + frow) * LDK + kk + fkq];
#pragma unroll
      for (int n = 0; n < 4; ++n) fb[n] = *(const short8_t*)&sW[(wc * 64 + n * 16 + frow) * LDK + kk + fkq];
#pragma unroll
      for (int m = 0; m < 4; ++m)
#pragma unroll
        for (int n = 0; n < 4; ++n)
          acc[m][n] = __builtin_amdgcn_mfma_f32_16x16x32_bf16(fa[m], fb[n], acc[m][n], 0, 0, 0);
    }
    __syncthreads();
  }
  const int crow = (lane >> 4) * 4, ccol = lane & 15;
#pragma unroll
  for (int n = 0; n < 4; ++n) {
    int col = bn * BN + wc * 64 + n * 16 + ccol;
#pragma unroll
    for (int m = 0; m < 4; ++m)
#pragma unroll
      for (int r = 0; r < 4; ++r) {
        int rowi = bm * BM + wr * 64 + m * 16 + crow + r;
        Cb[(size_t)rowi * N + col] = f2b(acc[m][n][r]);
      }
  }
}

// ===========================================================================
// step kernels: grid 256 = (bm 4)x(bn 64), block 512 = 8 waves (kg4 x nw2).
// gi: K=256, staged once into 80KB (sA 512B-rows @0, sW @32768).
// gh: K=2048 in 16 slices of 128, double-buffered 2x40KB (sA 256B-rows 16KB +
//     sW 24KB), raw-barrier pipeline w/ depth-3 register prefetch.
// swizzle: phys_slot = slot ^ (row & (nslots-1 lowbits)) -> 2-way-free reads.
// ===========================================================================
struct Args {
  const u16 *pairs, *Wenc, *whh1, *whh2, *wih2, *fc2T;
  const u16 *msB, *fc1wB;
  const float *ebi, *ebh, *dbi0, *dbi1, *dbh;
  const float *eps, *dec, *fc1_b, *fc2_b, *mu_b, *sg_b;
  float* hf;    // [2][256][2048]
  u16*   hbf;   // [2][256][2048]
  float* fbuf;  // [3][256][96]
  float* inp;   // [2][256][69]
  u16*   inpbf; // [2][256][128]
  u16*   fc1xB; // [256][192]
  float *out, *out_mu, *out_lv;
};

// gi compute: K=256 region (512B rows), swizzle slot^(r&7)
__device__ __forceinline__ void compute_gi(const char* sA, const char* sW,
    f32x4 (&aR)[4], f32x4 (&aZ)[4], f32x4 (&aN)[4], int kg, int nw, int lane) {
#pragma unroll
  for (int s = 0; s < 2; ++s) {
    const int L = kg * 8 + s * 4 + (lane >> 4);
    short8_t fa[4], fb[3];
#pragma unroll
    for (int m = 0; m < 4; ++m) {
      int r = m * 16 + (lane & 15);
      fa[m] = *(const short8_t*)&sA[r * 512 + ((L ^ (r & 7)) * 16)];
    }
#pragma unroll
    for (int g = 0; g < 3; ++g) {
      int r = nw * 48 + g * 16 + (lane & 15);
      fb[g] = *(const short8_t*)&sW[r * 512 + ((L ^ (r & 7)) * 16)];
    }
#pragma unroll
    for (int m = 0; m < 4; ++m) {
      aR[m] = __builtin_amdgcn_mfma_f32_16x16x32_bf16(fa[m], fb[0], aR[m], 0, 0, 0);
      aZ[m] = __builtin_amdgcn_mfma_f32_16x16x32_bf16(fa[m], fb[1], aZ[m], 0, 0, 0);
      aN[m] = __builtin_amdgcn_mfma_f32_16x16x32_bf16(fa[m], fb[2], aN[m], 0, 0, 0);
    }
  }
}

// gh compute: K=128 buffer (256B rows), swizzle slot^(r&15)
__device__ __forceinline__ void compute_gh(const char* base,
    f32x4 (&aR)[4], f32x4 (&aZ)[4], f32x4 (&aN)[4], int kg, int nw, int lane) {
  const char* sA = base;
  const char* sW = base + 16384;
  const int L = kg * 4 + (lane >> 4);
  short8_t fa[4], fb[3];
#pragma unroll
  for (int m = 0; m < 4; ++m) {
    int r = m * 16 + (lane & 15);
    fa[m] = *(const short8_t*)&sA[r * 256 + ((L ^ (r & 15)) * 16)];
  }
#pragma unroll
  for (int g = 0; g < 3; ++g) {
    int r = nw * 48 + g * 16 + (lane & 15);
    fb[g] = *(const short8_t*)&sW[r * 256 + ((L ^ (r & 15)) * 16)];
  }
#pragma unroll
  for (int m = 0; m < 4; ++m) {
    aR[m] = __builtin_amdgcn_mfma_f32_16x16x32_bf16(fa[m], fb[0], aR[m], 0, 0, 0);
    aZ[m] = __builtin_amdgcn_mfma_f32_16x16x32_bf16(fa[m], fb[1], aZ[m], 0, 0, 0);
    aN[m] = __builtin_amdgcn_mfma_f32_16x16x32_bf16(fa[m], fb[2], aN[m], 0, 0, 0);
  }
}

// 4-wave k-split reduce (3 LDS rounds) + in-register GRU gate (r4-proven)
__device__ __forceinline__ void reduce_and_gate(
    f32x4 (&aR)[4], f32x4 (&aZ)[4], f32x4 (&aNI)[4], f32x4 (&aNH)[4],
    char* smem, int tid, int bm, int bn,
    const float* __restrict__ bi, const float* __restrict__ bh,
    const float* __restrict__ hfold, float* __restrict__ hfnew, u16* __restrict__ hbnew) {
  const int lane = tid & 63, wid = tid >> 6;
  auto wr16 = [&](int slots, int w) {
#pragma unroll
    for (int m = 0; m < 4; ++m) {
      *(f32x4*)&smem[(((0 * 4 + m) * slots + w) * 64 + lane) * 16] = aR[m];
      *(f32x4*)&smem[(((1 * 4 + m) * slots + w) * 64 + lane) * 16] = aZ[m];
      *(f32x4*)&smem[(((2 * 4 + m) * slots + w) * 64 + lane) * 16] = aNI[m];
      *(f32x4*)&smem[(((3 * 4 + m) * slots + w) * 64 + lane) * 16] = aNH[m];
    }
  };
  auto add16 = [&](int slots, int w) {
#pragma unroll
    for (int m = 0; m < 4; ++m) {
      aR[m]  += *(const f32x4*)&smem[(((0 * 4 + m) * slots + w) * 64 + lane) * 16];
      aZ[m]  += *(const f32x4*)&smem[(((1 * 4 + m) * slots + w) * 64 + lane) * 16];
      aNI[m] += *(const f32x4*)&smem[(((2 * 4 + m) * slots + w) * 64 + lane) * 16];
      aNH[m] += *(const f32x4*)&smem[(((3 * 4 + m) * slots + w) * 64 + lane) * 16];
    }
  };
  __syncthreads();
  if (wid >= 4) wr16(4, wid - 4);
  __syncthreads();
  if (wid < 4) add16(4, wid);
  __syncthreads();
  if (wid == 2 || wid == 3) wr16(2, wid - 2);
  __syncthreads();
  if (wid < 2) {
    add16(2, wid);
    const int nw = wid, jj = lane & 15;
    const int Rb = bn * 96 + nw * 48;
    const float biR = bi[Rb + jj],      bhR = bh[Rb + jj];
    const float biZ = bi[Rb + 16 + jj], bhZ = bh[Rb + 16 + jj];
    const float biN = bi[Rb + 32 + jj], bhN = bh[Rb + 32 + jj];
    const int j = bn * 32 + nw * 16 + jj;
#pragma unroll
    for (int m = 0; m < 4; ++m)
#pragma unroll
      for (int q = 0; q < 4; ++q) {
        int b = bm * 64 + m * 16 + ((lane >> 4) << 2) + q;
        float r = sigm(aR[m][q] + biR + bhR);
        float z = sigm(aZ[m][q] + biZ + bhZ);
        float nn = 2.f * sigm(2.f * ((aNI[m][q] + biN) + r * (aNH[m][q] + bhN))) - 1.f;
        float hv = (1.f - z) * nn + z * hfold[(size_t)b * RNN + j];
        hfnew[(size_t)b * RNN + j] = hv;
        hbnew[(size_t)b * RNN + j] = f2b(hv);
      }
  }
}

// ---- encoder step ---------------------------------------------------------
__global__ __launch_bounds__(512, 1) void k_enc(Args a, int t) {
  __shared__ char smem[81920];
  const int tid = threadIdx.x, lane = tid & 63, wid = tid >> 6;
  const int kg = wid >> 1, nw = wid & 1;
  const int bm = blockIdx.x >> 6, bn = blockIdx.x & 63;
  const int rowA0 = bm * 64, rowW0 = bn * 96;
  const int pin = t & 1, pout = pin ^ 1;
  const u16* hin = a.hbf + (size_t)pin * B_ * RNN;
  const float* hfold = a.hf + (size_t)pin * B_ * RNN;
  float* hfnew = a.hf + (size_t)pout * B_ * RNN;
  u16* hbnew = a.hbf + (size_t)pout * B_ * RNN;
  const int sr32 = tid >> 5, sc32 = tid & 31;
  const int sr16 = tid >> 4, sc16 = tid & 15;

  f32x4 aR[4], aZ[4], aNI[4], aNH[4];
#pragma unroll
  for (int m = 0; m < 4; ++m) {
    aR[m] = (f32x4)(0.f); aZ[m] = (f32x4)(0.f);
    aNI[m] = (f32x4)(0.f); aNH[m] = (f32x4)(0.f);
  }

  auto issue_gh = [&](short8_t (&ra)[2], short8_t (&rw)[3], int k0) {
#pragma unroll
    for (int p = 0; p < 2; ++p) {
      int r = p * 32 + sr16;
      ra[p] = ldbf(hin, (size_t)(rowA0 + r) * RNN + k0 + sc16 * 8);
    }
#pragma unroll
    for (int p = 0; p < 3; ++p) {
      int r = p * 32 + sr16;
      rw[p] = ldbf(a.whh1, (size_t)(rowW0 + r) * RNN + k0 + sc16 * 8);
    }
  };
  auto write_gh = [&](char* base, short8_t (&ra)[2], short8_t (&rw)[3]) {
#pragma unroll
    for (int p = 0; p < 2; ++p) {
      int r = p * 32 + sr16;
      *(short8_t*)&base[r * 256 + ((sc16 ^ (r & 15)) * 16)] = ra[p];
    }
#pragma unroll
    for (int p = 0; p < 3; ++p) {
      int r = p * 32 + sr16;
      *(short8_t*)&(base + 16384)[r * 256 + ((sc16 ^ (r & 15)) * 16)] = rw[p];
    }
  };

  // ---- gi stage (80 KB region) ----
  {
    const u16* P = a.pairs + (size_t)t * B_ * 256;
    short8_t ga[4], gw[6];
#pragma unroll
    for (int p = 0; p < 4; ++p) {
      int r = p * 16 + sr32;
      ga[p] = ldbf(P, (size_t)(rowA0 + r) * 256 + sc32 * 8);
    }
#pragma unroll
    for (int p = 0; p < 6; ++p) {
      int r = p * 16 + sr32;
      gw[p] = ldbf(a.Wenc, (size_t)(rowW0 + r) * 256 + sc32 * 8);
    }
#pragma unroll
    for (int p = 0; p < 4; ++p) {
      int r = p * 16 + sr32;
      *(short8_t*)&smem[r * 512 + ((sc32 ^ (r & 7)) * 16)] = ga[p];
    }
#pragma unroll
    for (int p = 0; p < 6; ++p) {
      int r = p * 16 + sr32;
      *(short8_t*)&smem[32768 + r * 512 + ((sc32 ^ (r & 7)) * 16)] = gw[p];
    }
  }
  short8_t rA0[2], rW0[3], rA1[2], rW1[3];
  issue_gh(rA0, rW0, 0);          // ld0 -> S0
  issue_gh(rA1, rW1, 128);        // ld1 -> S1
  BARRIER();
  compute_gi(smem, smem + 32768, aR, aZ, aNI, kg, nw, lane);
  BARRIER();
  write_gh(smem, rA0, rW0);       // buf0 <- ld0
  issue_gh(rA0, rW0, 2 * 128);    // ld2 -> S0
  BARRIER();
#pragma unroll
  for (int i = 0; i < 16; ++i) {
    char* cb = (i & 1) ? smem + 40960 : smem;
    if (i + 1 <= 15) {
      char* nb = ((i + 1) & 1) ? smem + 40960 : smem;
      if ((i + 1) & 1) {
        write_gh(nb, rA1, rW1);
        if (i + 3 <= 15) issue_gh(rA1, rW1, (i + 3) * 128);
      } else {
        write_gh(nb, rA0, rW0);
        if (i + 3 <= 15) issue_gh(rA0, rW0, (i + 3) * 128);
      }
    }
    compute_gh(cb, aR, aZ, aNH, kg, nw, lane);
    if (i < 15) BARRIER();
  }
  reduce_and_gate(aR, aZ, aNI, aNH, smem, tid, bm, bn, a.ebi, a.ebh, hfold, hfnew, hbnew);
}

// ---- decoder step ---------------------------------------------------------
__global__ __launch_bounds__(512, 1) void k_dec(Args a, int t) {
  __shared__ char smem[81920];
  const int tid = threadIdx.x, lane = tid & 63, wid = tid >> 6;
  const int kg = wid >> 1, nw = wid & 1;
  const int bm = blockIdx.x >> 6, bn = blockIdx.x & 63;
  const int rowA0 = bm * 64, rowW0 = bn * 96;
  const int pin = t & 1, pout = pin ^ 1;
  const int irs = (t + 1) & 1, iws = t & 1;
  const int frd = (t + 2) % 3;
  const u16* hin = a.hbf + (size_t)pin * B_ * RNN;
  const float* hfold = a.hf + (size_t)pin * B_ * RNN;
  float* hfnew = a.hf + (size_t)pout * B_ * RNN;
  u16* hbnew = a.hbf + (size_t)pout * B_ * RNN;
  const int gtid = blockIdx.x * 512 + tid;
  const int sr32 = tid >> 5, sc32 = tid & 31;
  const int sr16 = tid >> 4, sc16 = tid & 15;
  const int fr = lane & 15, fq = (lane >> 4) << 3;

  // epilogue: out_{t-1} = inp_{t-1} + f_{t-1} + fc2_b ; write inp_t slot
  if (t >= 1 && gtid < B_ * INDIM) {
    int b = gtid / INDIM, o = gtid % INDIM;
    float v = a.inp[(size_t)irs * B_ * INDIM + gtid] +
              a.fbuf[(size_t)frd * B_ * 96 + b * 96 + o] + a.fc2_b[o];
    a.out[((size_t)b * TD + (t - 1)) * INDIM + o] = v;
    a.inp[(size_t)iws * B_ * INDIM + gtid] = v;
    a.inpbf[(size_t)iws * B_ * 128 + b * 128 + o] = f2b(v);
  }
  // zero f slot for step t+1
  if (gtid < B_ * 96)
    a.fbuf[(size_t)((t + 1) % 3) * B_ * 96 + gtid] = 0.f;

  f32x4 aR[4], aZ[4], aNI[4], aNH[4];
#pragma unroll
  for (int m = 0; m < 4; ++m) {
    aR[m] = (f32x4)(0.f); aZ[m] = (f32x4)(0.f);
    aNI[m] = (f32x4)(0.f); aNH[m] = (f32x4)(0.f);
  }

  auto issue_gh = [&](short8_t (&ra)[2], short8_t (&rw)[3], int k0) {
#pragma unroll
    for (int p = 0; p < 2; ++p) {
      int r = p * 32 + sr16;
      ra[p] = ldbf(hin, (size_t)(rowA0 + r) * RNN + k0 + sc16 * 8);
    }
#pragma unroll
    for (int p = 0; p < 3; ++p) {
      int r = p * 32 + sr16;
      rw[p] = ldbf(a.whh2, (size_t)(rowW0 + r) * RNN + k0 + sc16 * 8);
    }
  };
  auto write_gh = [&](char* base, short8_t (&ra)[2], short8_t (&rw)[3]) {
#pragma unroll
    for (int p = 0; p < 2; ++p) {
      int r = p * 32 + sr16;
      *(short8_t*)&base[r * 256 + ((sc16 ^ (r & 15)) * 16)] = ra[p];
    }
#pragma unroll
    for (int p = 0; p < 3; ++p) {
      int r = p * 32 + sr16;
      *(short8_t*)&(base + 16384)[r * 256 + ((sc16 ^ (r & 15)) * 16)] = rw[p];
    }
  };

  // ---- gi stage: A = [inp_{t-1} | bf16(f_{t-1}) pad], W = [wih2 | wih2] ----
  {
    const u16* inpA = a.inpbf + (size_t)irs * B_ * 128;
    const float* F = a.fbuf + (size_t)frd * B_ * 96;
    short8_t ga[4], gw[6];
#pragma unroll
    for (int p = 0; p < 4; ++p) {
      int r = p * 16 + sr32;
      if (sc32 < 16) {
        ga[p] = ldbf(inpA, (size_t)(rowA0 + r) * 128 + sc32 * 8);
      } else {
        short8_t v;
        int o0 = (sc32 - 16) * 8;
#pragma unroll
        for (int e = 0; e < 8; ++e) {
          int o = o0 + e;
          float fv = (o < 96) ? F[(size_t)(rowA0 + r) * 96 + o] : 0.f;
          v[e] = (short)f2b(fv);
        }
        ga[p] = v;
      }
    }
#pragma unroll
    for (int p = 0; p < 6; ++p) {
      int r = p * 16 + sr32;
      gw[p] = ldbf(a.wih2, (size_t)(rowW0 + r) * 128 + (sc32 & 15) * 8);
    }
#pragma unroll
    for (int p = 0; p < 4; ++p) {
      int r = p * 16 + sr32;
      *(short8_t*)&smem[r * 512 + ((sc32 ^ (r & 7)) * 16)] = ga[p];
    }
#pragma unroll
    for (int p = 0; p < 6; ++p) {
      int r = p * 16 + sr32;
      *(short8_t*)&smem[32768 + r * 512 + ((sc32 ^ (r & 7)) * 16)] = gw[p];
    }
  }
  short8_t rA0[2], rW0[3], rA1[2], rW1[3];
  issue_gh(rA0, rW0, 0);
  issue_gh(rA1, rW1, 128);
  BARRIER();
  compute_gi(smem, smem + 32768, aR, aZ, aNI, kg, nw, lane);
  BARRIER();
  write_gh(smem, rA0, rW0);
  issue_gh(rA0, rW0, 2 * 128);
  BARRIER();
#pragma unroll
  for (int i = 0; i < 16; ++i) {
    char* cb = (i & 1) ? smem + 40960 : smem;
    if (i + 1 <= 15) {
      char* nb = ((i + 1) & 1) ? smem + 40960 : smem;
      if ((i + 1) & 1) {
        write_gh(nb, rA1, rW1);
        if (i + 3 <= 15) issue_gh(rA1, rW1, (i + 3) * 128);
      } else {
        write_gh(nb, rA0, rW0);
        if (i + 3 <= 15) issue_gh(rA0, rW0, (i + 3) * 128);
      }
    }
    compute_gh(cb, aR, aZ, aNH, kg, nw, lane);
    if (i < 15) BARRIER();
  }
  reduce_and_gate(aR, aZ, aNI, aNH, smem, tid, bm, bn,
                  (t >= 1) ? a.dbi1 : a.dbi0, a.dbh, hfold, hfnew, hbnew);

  // ---- f_t partial: fbuf[t%3][bm rows][96] += h'[rows][k=bn*32..] @ fc2T^T
  __syncthreads();   // h' writes done block-wide (r5-verified pattern)
  if (wid < 4) {
    const int wr = wid >> 1, wc = wid & 1;
    const int kcol = bn * 32 + fq;
    short8_t fa[2], fb[3];
#pragma unroll
    for (int m = 0; m < 2; ++m)
      fa[m] = ldbf(hbnew, (size_t)(bm * 64 + wr * 32 + m * 16 + fr) * RNN + kcol);
#pragma unroll
    for (int n = 0; n < 3; ++n)
      fb[n] = ldbf(a.fc2T, (size_t)(wc * 48 + n * 16 + fr) * RNN + kcol);
    f32x4 accf[2][3];
#pragma unroll
    for (int m = 0; m < 2; ++m)
#pragma unroll
      for (int n = 0; n < 3; ++n) accf[m][n] = (f32x4)(0.f);
#pragma unroll
    for (int m = 0; m < 2; ++m)
#pragma unroll
      for (int n = 0; n < 3; ++n)
        accf[m][n] = __builtin_amdgcn_mfma_f32_16x16x32_bf16(fa[m], fb[n], accf[m][n], 0, 0, 0);
    float* fdst = a.fbuf + (size_t)(t % 3) * B_ * 96;
#pragma unroll
    for (int m = 0; m < 2; ++m)
#pragma unroll
      for (int n = 0; n < 3; ++n)
#pragma unroll
        for (int q = 0; q < 4; ++q) {
          int row = bm * 64 + wr * 32 + m * 16 + ((lane >> 4) << 2) + q;
          int col = wc * 48 + n * 16 + (lane & 15);
          atomicAdd(&fdst[row * 96 + col], accf[m][n][q]);
        }
  }
}

// ---- latent mu/sigma MFMA (r5-verified) -----------------------------------
__global__ __launch_bounds__(256) void k_msm(Args a) {
  const int bm = blockIdx.x >> 3, kc = blockIdx.x & 7;
  const int lane = threadIdx.x & 63, wid = threadIdx.x >> 6;
  const int wr = wid >> 1, wc = wid & 1;
  const int fr = lane & 15, fq = (lane >> 4) << 3;
  const u16* h1 = a.hbf + (size_t)B_ * RNN;
  f32x4 acc[4][4];
#pragma unroll
  for (int m = 0; m < 4; ++m)
#pragma unroll
    for (int n = 0; n < 4; ++n) acc[m][n] = (f32x4)(0.f);
#pragma unroll
  for (int ks = 0; ks < 8; ++ks) {
    const int k = kc * 256 + ks * 32 + fq;
    short8_t fa[4], fb[4];
#pragma unroll
    for (int m = 0; m < 4; ++m)
      fa[m] = ldbf(h1, (size_t)(bm * 128 + wr * 64 + m * 16 + fr) * RNN + k);
#pragma unroll
    for (int n = 0; n < 4; ++n)
      fb[n] = ldbf(a.msB, (size_t)(wc * 64 + n * 16 + fr) * RNN + k);
#pragma unroll
    for (int m = 0; m < 4; ++m)
#pragma unroll
      for (int n = 0; n < 4; ++n)
        acc[m][n] = __builtin_amdgcn_mfma_f32_16x16x32_bf16(fa[m], fb[n], acc[m][n], 0, 0, 0);
  }
#pragma unroll
  for (int m = 0; m < 4; ++m)
#pragma unroll
    for (int n = 0; n < 4; ++n)
#pragma unroll
      for (int q = 0; q < 4; ++q) {
        int row = bm * 128 + wr * 64 + m * 16 + ((lane >> 4) << 2) + q;
        int col = wc * 64 + n * 16 + (lane & 15);
        if (col < NZ) atomicAdd(&a.out_mu[row * NZ + col], acc[m][n][q]);
        else          atomicAdd(&a.out_lv[row * NZ + col - NZ], acc[m][n][q]);
      }
}

// ---- sample + fc1 input + decoder inp init (r5-verified) ------------------
__global__ void k_sample(Args a) {
  int gid = blockIdx.x * blockDim.x + threadIdx.x;
  if (gid < B_ * NZ) {
    int b = gid >> 6, n = gid & 63;
    float mu = a.out_mu[gid] + a.mu_b[n];
    float lv = a.out_lv[gid] + a.sg_b[n];
    a.out_mu[gid] = mu;
    a.out_lv[gid] = lv;
    a.fc1xB[b * 192 + n] = f2b(mu + a.eps[gid] * __expf(0.5f * lv));
  }
  if (gid < B_ * 128) {
    int b = gid >> 7, c = gid & 127;
    float v = (c < INDIM) ? a.dec[(size_t)b * TD * INDIM + c] : 0.f;
    u16 vb = f2b(v);
    a.inpbf[(size_t)b * 128 + c] = vb;
    a.inpbf[(size_t)B_ * 128 + b * 128 + c] = vb;
    if (c < INDIM) {
      a.inp[b * INDIM + c] = v;
      a.inp[B_ * INDIM + b * INDIM + c] = v;
      a.fc1xB[b * 192 + NZ + c] = f2b(v);
    }
  }
  if (gid < B_ * 192) {
    int c = gid % 192;
    if (c >= NZ + INDIM) a.fc1xB[gid] = 0;
  }
}

// ---- fc1 MFMA (r5-verified) -----------------------------------------------
__global__ __launch_bounds__(256) void k_fc1m(Args a) {
  const int bm = blockIdx.x >> 4, bn = blockIdx.x & 15;
  const int lane = threadIdx.x & 63, wid = threadIdx.x >> 6;
  const int wr = wid >> 1, wc = wid & 1;
  const int fr = lane & 15, fq = (lane >> 4) << 3;
  f32x4 acc[4][4];
#pragma unroll
  for (int m = 0; m < 4; ++m)
#pragma unroll
    for (int n = 0; n < 4; ++n) acc[m][n] = (f32x4)(0.f);
#pragma unroll
  for (int ks = 0; ks < 6; ++ks) {
    const int k = ks * 32 + fq;
    short8_t fa[4], fb[4];
#pragma unroll
    for (int m = 0; m < 4; ++m)
      fa[m] = ldbf(a.fc1xB, (size_t)(bm * 128 + wr * 64 + m * 16 + fr) * 192 + k);
#pragma unroll
    for (int n = 0; n < 4; ++n)
      fb[n] = ldbf(a.fc1wB, (size_t)(bn * 128 + wc * 64 + n * 16 + fr) * 192 + k);
#pragma unroll
    for (int m = 0; m < 4; ++m)
#pragma unroll
      for (int n = 0; n < 4; ++n)
        acc[m][n] = __builtin_amdgcn_mfma_f32_16x16x32_bf16(fa[m], fb[n], acc[m][n], 0, 0, 0);
  }
#pragma unroll
  for (int n = 0; n < 4; ++n) {
    const int col = bn * 128 + wc * 64 + n * 16 + (lane & 15);
    const float bv = a.fc1_b[col];
#pragma unroll
    for (int m = 0; m < 4; ++m)
#pragma unroll
      for (int q = 0; q < 4; ++q) {
        int row = bm * 128 + wr * 64 + m * 16 + ((lane >> 4) << 2) + q;
        float v = acc[m][n][q] + bv;
        a.hf[(size_t)row * RNN + col] = v;
        a.hbf[(size_t)row * RNN + col] = f2b(v);
      }
  }
}

// ---- tail: out_24 ----------------------------------------------------------
__global__ void k_tail(Args a) {
  int i = blockIdx.x * blockDim.x + threadIdx.x;
  if (i < B_ * INDIM) {
    int b = i / INDIM, o = i % INDIM;
    float v = a.inp[(size_t)(24 & 1) * B_ * INDIM + i] +
              a.fbuf[(size_t)(24 % 3) * B_ * 96 + b * 96 + o] + a.fc2_b[o];
    a.out[((size_t)b * TD + 24) * INDIM + o] = v;
  }
}

// ===========================================================================
extern "C" void kernel_launch(void* const* d_in, const int* in_sizes, int n_in,
                              void* d_out, int out_size, void* d_ws, size_t ws_size,
                              hipStream_t stream)
{
  const float* enc    = (const float*)d_in[0];
  const float* dec    = (const float*)d_in[1];
  const float* eps    = (const float*)d_in[2];
  const float* fc0_w  = (const float*)d_in[3];
  const float* fc0_b  = (const float*)d_in[4];
  const float* fc1_w  = (const float*)d_in[5];
  const float* fc1_b  = (const float*)d_in[6];
  const float* fc2_w  = (const float*)d_in[7];
  const float* fc2_b  = (const float*)d_in[8];
  const float* mu_w   = (const float*)d_in[9];
  const float* mu_b   = (const float*)d_in[10];
  const float* sg_w   = (const float*)d_in[11];
  const float* sg_b   = (const float*)d_in[12];
  const float* c1_wih = (const float*)d_in[13];
  const float* c1_whh = (const float*)d_in[14];
  const float* c1_bih = (const float*)d_in[15];
  const float* c1_bhh = (const float*)d_in[16];
  const float* c2_wih = (const float*)d_in[17];
  const float* c2_whh = (const float*)d_in[18];
  const float* c2_bih = (const float*)d_in[19];
  const float* c2_bhh = (const float*)d_in[20];

  float* out_outputs = (float*)d_out;
  float* out_mu = out_outputs + (size_t)B_ * TD * INDIM;
  float* out_lv = out_mu + (size_t)B_ * NZ;

  char* ws = (char*)d_ws;
  size_t off = 0;
  auto alloc = [&](size_t bytes) -> void* {
    void* p = ws + off; off += (bytes + 255) & ~(size_t)255; return p;
  };

  u16* whh1_r = (u16*)alloc((size_t)G3 * RNN * 2);
  u16* whh2_r = (u16*)alloc((size_t)G3 * RNN * 2);
  u16* wih1_r = (u16*)alloc((size_t)G3 * RNN * 2);
  u16* wih2_r = (u16*)alloc((size_t)G3 * 128 * 2);
  u16* fc0T   = (u16*)alloc((size_t)256 * RNN * 2);
  u16* fc2T   = (u16*)alloc((size_t)96 * RNN * 2);
  u16* Wenc   = (u16*)alloc((size_t)G3 * 256 * 2);
  u16* pairs  = (u16*)alloc((size_t)SE * B_ * 256 * 2);
  u16* msB    = (u16*)alloc((size_t)128 * RNN * 2);
  u16* fc1wB  = (u16*)alloc((size_t)RNN * 192 * 2);
  float* hf   = (float*)alloc((size_t)2 * B_ * RNN * 4);
  u16* hbf    = (u16*)alloc((size_t)2 * B_ * RNN * 2);
  float* fbuf = (float*)alloc((size_t)3 * B_ * 96 * 4);
  float* inp  = (float*)alloc((size_t)2 * B_ * INDIM * 4);
  u16* inpbf  = (u16*)alloc((size_t)2 * B_ * 128 * 2);
  u16* fc1xB  = (u16*)alloc((size_t)B_ * 192 * 2);
  float* ebi  = (float*)alloc((size_t)G3 * 4);
  float* ebh  = (float*)alloc((size_t)G3 * 4);
  float* dbi0 = (float*)alloc((size_t)G3 * 4);
  float* dbi1 = (float*)alloc((size_t)G3 * 4);
  float* dbh  = (float*)alloc((size_t)G3 * 4);
  (void)ws_size; (void)in_sizes; (void)n_in; (void)out_size;

  // ---- prep ----
  k_reorder<<<4096, 256, 0, stream>>>(c1_whh, whh1_r, RNN, RNN);
  k_reorder<<<4096, 256, 0, stream>>>(c2_whh, whh2_r, RNN, RNN);
  k_reorder<<<4096, 256, 0, stream>>>(c1_wih, wih1_r, RNN, RNN);
  k_reorder<<<1024, 256, 0, stream>>>(c2_wih, wih2_r, INDIM, 128);
  k_fc0T<<<512, 256, 0, stream>>>(fc0_w, fc0_b, fc0T);
  k_fc2T<<<256, 256, 0, stream>>>(fc2_w, fc2T);
  k_pairs<<<2048, 256, 0, stream>>>(enc, dec, pairs);
  k_msB<<<256, 256, 0, stream>>>(mu_w, sg_w, msB);
  k_fc1B<<<256, 256, 0, stream>>>(fc1_w, fc1wB);
  k_bias<<<24, 256, 0, stream>>>(c1_bih, c1_bhh, c2_wih, fc2_b, c2_bih, c2_bhh,
                                 ebi, ebh, dbi0, dbi1, dbh);

  Args a;
  a.pairs = pairs; a.Wenc = Wenc; a.whh1 = whh1_r; a.whh2 = whh2_r;
  a.wih2 = wih2_r; a.fc2T = fc2T; a.msB = msB; a.fc1wB = fc1wB;
  a.ebi = ebi; a.ebh = ebh; a.dbi0 = dbi0; a.dbi1 = dbi1; a.dbh = dbh;
  a.eps = eps; a.dec = dec; a.fc1_b = fc1_b; a.fc2_b = fc2_b;
  a.mu_b = mu_b; a.sg_b = sg_b;
  a.hf = hf; a.hbf = hbf; a.fbuf = fbuf; a.inp = inp; a.inpbf = inpbf;
  a.fc1xB = fc1xB; a.out = out_outputs; a.out_mu = out_mu; a.out_lv = out_lv;

  k_init<<<2048, 256, 0, stream>>>(hf, hbf, fbuf, out_mu, out_lv);
  gemm_bt<<<(G3 / 128) * (256 / 128), 256, 0, stream>>>(wih1_r, fc0T, Wenc, 256, RNN);

  for (int t = 0; t < SE; ++t)
    k_enc<<<256, 512, 0, stream>>>(a, t);
  k_msm<<<16, 256, 0, stream>>>(a);
  k_sample<<<192, 256, 0, stream>>>(a);
  k_fc1m<<<32, 256, 0, stream>>>(a);
  for (int t = 0; t < TD; ++t)
    k_dec<<<256, 512, 0, stream>>>(a, t);
  k_tail<<<69, 256, 0, stream>>>(a);
}